// Round 24
// baseline (571.772 us; speedup 1.0000x reference)
//
#include <hip/hip_runtime.h>
#include <math.h>

#define BROWS 32768
#define DIM   1024
#define NLAT  64
#define NS    32
#define NL    256
#define RPB   32    // rows per block

// ---------------- prep kernel (proven) ----------------

__global__ void prep_w2(const float* __restrict__ sq_w,
                        const float* __restrict__ sbank,
                        const float* __restrict__ sq_b,
                        double* __restrict__ W2d,
                        double* __restrict__ sconst)
{
    int t = blockIdx.x * blockDim.x + threadIdx.x;   // 32768 threads
    int s = t & (NS - 1);
    int d = t >> 5;
    const float* wr = sq_w + (size_t)d * DIM;
    const float* br = sbank + (size_t)s * DIM;
    double acc = 0.0;
    for (int o = 0; o < DIM; ++o) acc += (double)wr[o] * (double)br[o];
    W2d[(size_t)d * NS + s] = acc * 0.03125;
    if (d == 0) {
        double c = 0.0;
        for (int o = 0; o < DIM; ++o) c += (double)sq_b[o] * (double)br[o];
        sconst[s] = c * 0.03125;
    }
}

// ---------------- helpers ----------------

__device__ __forceinline__ void fma4(float4& A, float wgt, const float4& v) {
    A.x += wgt * v.x; A.y += wgt * v.y; A.z += wgt * v.z; A.w += wgt * v.w;
}

// numpy SIMD f32 exp emulation (Cephes-derived poly, FMA Horner, rint quadrant).
__device__ __forceinline__ float np_expf(float x) {
    float m = rintf(x * 1.44269504088896341f);
    float r = fmaf(m, -0.693359375f, x);
    r = fmaf(m, 2.12194440e-4f, r);
    float y = 1.9875691500E-4f;
    y = fmaf(y, r, 1.3981999507E-3f);
    y = fmaf(y, r, 8.3334519073E-3f);
    y = fmaf(y, r, 4.1665795894E-2f);
    y = fmaf(y, r, 1.6666665459E-1f);
    y = fmaf(y, r, 5.0000001201E-1f);
    float r2 = r * r;
    y = fmaf(y, r2, r);
    y = y + 1.0f;
    return ldexpf(y, (int)m);
}

// ---------------- main fused kernel ----------------

__global__ __launch_bounds__(512, 6)
void hmb_main(const float* __restrict__ query,
              const float* __restrict__ qw,      // q_w (1024x64)
              const float* __restrict__ qb,      // q_b (64)
              const double* __restrict__ W2d,    // (1024x32) f64, pre-scaled
              const double* __restrict__ sconst, // (32) f64
              const float* __restrict__ lbank,   // (256x64)
              const float* __restrict__ dec_w,   // (64x1024)
              const float* __restrict__ dec_b,   // (1024)
              const float* __restrict__ sbank,   // (32x1024)
              float* __restrict__ out)
{
    __shared__ __align__(16) unsigned char raw[33920];
    float  (*LqF)[64]  = (float  (*)[64])(raw);            // [    0,  8192) A1->A2a
    float  (*Sc)[256]  = (float  (*)[256])(raw + 8192);    // [ 8192, 24576) 16-row pass
    float  (*Wd)[256]  = (float  (*)[256])(raw);           // [    0, 16384) phase-3 overlay
    float  (*Zl)[64]   = (float  (*)[64])(raw + 24576);    // [24576, 32768)
    int    (*SWi)[4]   = (int    (*)[4])(raw + 32768);     // [32768, 33280)
    float  (*SWv)[4]   = (float  (*)[4])(raw + 33280);     // [33280, 33792)
    float  *SLT        = (float  *)(raw + 33792);          // [33792, 33920)

    const int t    = threadIdx.x;     // 0..511
    const int lane = t & 63;
    const int wv   = t >> 6;          // 0..7
    const int row0 = blockIdx.x * RPB;

    const size_t OS_SIDX = 33554432ull;
    const size_t OS_LIDX = 33685504ull;
    const size_t OS_STOP = 33947648ull;
    const size_t OS_LTOP = 34078720ull;

    // ==== phase A1 (+B1 merged): wave wv owns rows 4wv..4wv+3 ====
    // f32 lq KC=384 panels (scalar q loads); f64 short logits alongside
    double av0 = 0, av1 = 0;
    const int  sIdx = lane & 31;
    const bool hi   = lane >= 32;     // hi lanes: f64 rows 2,3 of the quad
    {
        const int wvu = __builtin_amdgcn_readfirstlane(wv);
        const float* qrow = query + (size_t)(row0 + 4 * wvu) * DIM;
        float lt[4] = {0, 0, 0, 0};
#pragma unroll 1
        for (int s = 0; s < 3; ++s) {
            const int dlo = s * 384;
            const int dhi = (s == 2) ? 1024 : (dlo + 384);
            float la[4] = {0, 0, 0, 0};
#pragma unroll 4
            for (int d = dlo; d < dhi; ++d) {
                float wl = qw[(size_t)d * NLAT + lane];
                float q0 = qrow[d];
                float q1 = qrow[DIM + d];
                float q2 = qrow[2 * DIM + d];
                float q3 = qrow[3 * DIM + d];
                la[0] = fmaf(q0, wl, la[0]);
                la[1] = fmaf(q1, wl, la[1]);
                la[2] = fmaf(q2, wl, la[2]);
                la[3] = fmaf(q3, wl, la[3]);
                double w2 = W2d[(size_t)d * NS + sIdx];
                av0 = fma((double)(hi ? q2 : q0), w2, av0);
                av1 = fma((double)(hi ? q3 : q1), w2, av1);
            }
#pragma unroll
            for (int i = 0; i < 4; ++i) lt[i] += la[i];   // panel commits ((p0+p1)+p2)
        }
        float qbl = qb[lane];
#pragma unroll
        for (int i = 0; i < 4; ++i)
            LqF[4 * wvu + i][lane] = lt[i] + qbl;
    }
    __syncthreads();   // LqF ready

    // ============ phase A2: two passes of 16 rows (2 octets in parallel) ============
    const int slot = t & 255;         // slot for A2a
    const int oct  = t >> 8;          // 0 or 1: row-octet within the pass
#pragma unroll 1
    for (int p = 0; p < 2; ++p) {
        // ---- A2a: scores, (slot, octet) per thread, 8 rows (bit-exact chains) ----
        {
            float acc[8];
#pragma unroll
            for (int rr = 0; rr < 8; ++rr) acc[rr] = 0.0f;
            const float4* lb4 = (const float4*)(lbank + (size_t)slot * NLAT);
#pragma unroll 1
            for (int jq = 0; jq < 16; ++jq) {
                float4 b = lb4[jq];
#pragma unroll
                for (int rr = 0; rr < 8; ++rr) {
                    float4 q4v = *(const float4*)&LqF[16 * p + 8 * oct + rr][4 * jq];
                    float a = acc[rr];
                    a = fmaf(q4v.x, b.x, a);
                    a = fmaf(q4v.y, b.y, a);
                    a = fmaf(q4v.z, b.z, a);
                    a = fmaf(q4v.w, b.w, a);
                    acc[rr] = a;
                }
            }
#pragma unroll
            for (int rr = 0; rr < 8; ++rr) Sc[8 * oct + rr][slot] = acc[rr] * 0.125f;
        }
        __syncthreads();   // Sc ready

        // ---- A2b: 2 rows per wave (rh = 2wv+rg over 16 rows) ----
#pragma unroll 1
        for (int rg = 0; rg < 2; ++rg) {
            const int rh  = 2 * wv + rg;
            const int row = 16 * p + rh;
            const size_t grow = (size_t)(row0 + row);
            float c0 = Sc[rh][lane],       c1 = Sc[rh][lane + 64],
                  c2 = Sc[rh][lane + 128], c3 = Sc[rh][lane + 192];
            float m = fmaxf(fmaxf(c0, c1), fmaxf(c2, c3));
#pragma unroll
            for (int off = 32; off > 0; off >>= 1)
                m = fmaxf(m, __shfl_xor(m, off, 64));
            float e0 = np_expf(c0 - m), e1 = np_expf(c1 - m),
                  e2 = np_expf(c2 - m), e3 = np_expf(c3 - m);
            // denominator: exact numpy AVX512 pairwise tree via shuffles
            float A0 = e0 + __shfl_down(e0, 16, 64);
            float B0 = __shfl_down(e0, 32, 64) + __shfl_down(e0, 48, 64);
            float C0 = e1 + __shfl_down(e1, 16, 64);
            float D0 = __shfl_down(e1, 32, 64) + __shfl_down(e1, 48, 64);
            float R0 = (A0 + B0) + (C0 + D0);
            float A1_ = e2 + __shfl_down(e2, 16, 64);
            float B1_ = __shfl_down(e2, 32, 64) + __shfl_down(e2, 48, 64);
            float C1_ = e3 + __shfl_down(e3, 16, 64);
            float D1_ = __shfl_down(e3, 32, 64) + __shfl_down(e3, 48, 64);
            float R1 = (A1_ + B1_) + (C1_ + D1_);
            float t0 = R0 + __shfl_down(R0, 8, 64);
            float u0 = t0 + __shfl_down(t0, 4, 64);
            float f0 = (u0 + __shfl_down(u0, 2, 64)) + (__shfl_down(u0, 1, 64) + __shfl_down(u0, 3, 64));
            float t1 = R1 + __shfl_down(R1, 8, 64);
            float u1 = t1 + __shfl_down(t1, 4, 64);
            float f1 = (u1 + __shfl_down(u1, 2, 64)) + (__shfl_down(u1, 1, 64) + __shfl_down(u1, 3, 64));
            float sden = __shfl(f0 + f1, 0, 64);
            float v0 = e0 / sden, v1 = e1 / sden, v2 = e2 / sden, v3 = e3 / sden;
            // top-8 butterfly: strict >, lowest index on ties
            float ltv[8]; int lwi[8];
#pragma unroll
            for (int it = 0; it < 8; ++it) {
                float v = v0; int u = 0;
                if (v1 > v) { v = v1; u = 1; }
                if (v2 > v) { v = v2; u = 2; }
                if (v3 > v) { v = v3; u = 3; }
                int gi = lane + (u << 6);
#pragma unroll
                for (int off = 32; off > 0; off >>= 1) {
                    float ov = __shfl_xor(v, off, 64);
                    int og = __shfl_xor(gi, off, 64);
                    if (ov > v || (ov == v && og < gi)) { v = ov; gi = og; }
                }
                ltv[it] = v; lwi[it] = gi;
                if ((gi & 63) == lane) {
                    int wu = gi >> 6;
                    if      (wu == 0) v0 = -1.0e30f;
                    else if (wu == 1) v1 = -1.0e30f;
                    else if (wu == 2) v2 = -1.0e30f;
                    else              v3 = -1.0e30f;
                }
            }
            float zv = 0.0f;
#pragma unroll
            for (int k = 0; k < 8; ++k)
                zv += ltv[k] * lbank[(size_t)lwi[k] * NLAT + lane];
            Zl[row][lane] = zv;
            if (lane == 0) {
                SLT[row] = ltv[0]+ltv[1]+ltv[2]+ltv[3]+ltv[4]+ltv[5]+ltv[6]+ltv[7];
            } else if (lane == 1) {
                float* pi = out + OS_LIDX + grow * 8;
                float* pt = out + OS_LTOP + grow * 8;
#pragma unroll
                for (int k = 0; k < 8; ++k) { pi[k] = (float)lwi[k]; pt[k] = ltv[k]; }
            }
        }
        __syncthreads();   // Sc consumed; next pass / phase 3 may proceed
    }

    // ============ phase B2: short top-4 butterfly (av in regs, shfl broadcast) ======
    {
        double scv = sconst[sIdx];
#pragma unroll
        for (int rg = 0; rg < 4; ++rg) {
            const int r = 4 * wv + rg;
            const size_t grow = (size_t)(row0 + r);
            double avc = (rg & 1) ? av1 : av0;
            int src = (lane & 31) + ((rg & 2) ? 32 : 0);
            double pv = __shfl(avc, src, 64);
            double sx0 = (lane < NS) ? (pv + scv) : -1.0e300;
            double sx = sx0;
            double swv_[4]; int swi_[4];
#pragma unroll
            for (int it = 0; it < 4; ++it) {
                double v = sx; int ix = lane;
#pragma unroll
                for (int off = 32; off > 0; off >>= 1) {
                    double ov = __shfl_xor(v, off, 64);
                    int oi = __shfl_xor(ix, off, 64);
                    if (ov > v || (ov == v && oi < ix)) { v = ov; ix = oi; }
                }
                swv_[it] = v; swi_[it] = ix;
                if (lane == ix) sx = -1.0e300;
            }
            double sm = swv_[0];
            double ssum = (lane < NS) ? (double)expf((float)(sx0 - sm)) : 0.0;
#pragma unroll
            for (int off = 32; off > 0; off >>= 1) ssum += __shfl_xor(ssum, off, 64);
            float stv[4];
#pragma unroll
            for (int it = 0; it < 4; ++it)
                stv[it] = (float)((double)expf((float)(swv_[it] - sm)) / ssum);

            if (lane == 0) {
#pragma unroll
                for (int k = 0; k < 4; ++k) { SWi[r][k] = swi_[k]; SWv[r][k] = stv[k]; }
                float* ps = out + OS_SIDX + grow * 4;
                float* pt = out + OS_STOP + grow * 4;
#pragma unroll
                for (int k = 0; k < 4; ++k) { ps[k] = (float)swi_[k]; pt[k] = stv[k]; }
            }
        }
    }

    // ============ phase 3: rows 4wv..4wv+3; dec_w staged 16 rows; z via float4 ======
    const int col4 = t & 63;

#pragma unroll 1
    for (int dc = 0; dc < 4; ++dc) {
        const int cbase = dc * 256 + 4 * col4;
        float4 db = *(const float4*)(dec_b + cbase);
        float4 acc3[4];
#pragma unroll
        for (int r8 = 0; r8 < 4; ++r8) {
            const int row = 4 * wv + r8;
            float slt = SLT[row];
            float4 a;
            a.x = slt * db.x; a.y = slt * db.y; a.z = slt * db.z; a.w = slt * db.w;
#pragma unroll
            for (int k = 0; k < 4; ++k) {
                int   si = SWi[row][k];
                float sv = SWv[row][k];
                float4 sb = *(const float4*)(sbank + (size_t)si * DIM + cbase);
                fma4(a, sv, sb);
            }
            acc3[r8] = a;
        }
#pragma unroll 1
        for (int jh = 0; jh < 4; ++jh) {
            __syncthreads();   // prior Wd readers done before restage
#pragma unroll
            for (int i = 0; i < 2; ++i) {
                int e = t + 512 * i;           // 0..1023
                int jr = e >> 6, c4 = e & 63;
                *(float4*)&Wd[jr][4 * c4] =
                    *(const float4*)(dec_w + (size_t)(16 * jh + jr) * DIM + dc * 256 + 4 * c4);
            }
            __syncthreads();
#pragma unroll 1
            for (int j2g = 0; j2g < 4; ++j2g) {
                float4 w40 = *(const float4*)&Wd[4 * j2g + 0][4 * col4];
                float4 w41 = *(const float4*)&Wd[4 * j2g + 1][4 * col4];
                float4 w42 = *(const float4*)&Wd[4 * j2g + 2][4 * col4];
                float4 w43 = *(const float4*)&Wd[4 * j2g + 3][4 * col4];
#pragma unroll
                for (int r8 = 0; r8 < 4; ++r8) {
                    float4 zv = *(const float4*)&Zl[4 * wv + r8][16 * jh + 4 * j2g];
                    fma4(acc3[r8], zv.x, w40);
                    fma4(acc3[r8], zv.y, w41);
                    fma4(acc3[r8], zv.z, w42);
                    fma4(acc3[r8], zv.w, w43);
                }
            }
        }
#pragma unroll
        for (int r8 = 0; r8 < 4; ++r8) {
            const int row = 4 * wv + r8;
            *(float4*)(out + (size_t)(row0 + row) * DIM + cbase) = acc3[r8];
        }
    }
}

// ---------------- launcher ----------------

extern "C" void kernel_launch(void* const* d_in, const int* in_sizes, int n_in,
                              void* d_out, int out_size, void* d_ws, size_t ws_size,
                              hipStream_t stream) {
    const float* query = (const float*)d_in[0];
    const float* sbank = (const float*)d_in[1];
    const float* lbank = (const float*)d_in[2];
    const float* dec_w = (const float*)d_in[3];
    const float* dec_b = (const float*)d_in[4];
    const float* q_w   = (const float*)d_in[5];
    const float* q_b   = (const float*)d_in[6];
    const float* sq_w  = (const float*)d_in[7];
    const float* sq_b  = (const float*)d_in[8];
    float* out = (float*)d_out;

    char* ws = (char*)d_ws;
    double* W2d    = (double*)(ws);             // [0, 262144)
    double* sconst = (double*)(ws + 262144);    // [262144, 262400)

    prep_w2 <<<dim3(128), dim3(256), 0, stream>>>(sq_w, sbank, sq_b, W2d, sconst);
    hmb_main<<<dim3(BROWS / RPB), dim3(512), 0, stream>>>(
        query, q_w, q_b, W2d, sconst, lbank, dec_w, dec_b, sbank, out);
}

// Round 25
// 526.713 us; speedup vs baseline: 1.0855x; 1.0855x over previous
//
#include <hip/hip_runtime.h>
#include <math.h>

#define BROWS 32768
#define DIM   1024
#define NLAT  64
#define NS    32
#define NL    256
#define RPB   32    // rows per block

// ---------------- prep kernel (proven) ----------------

__global__ void prep_w2(const float* __restrict__ sq_w,
                        const float* __restrict__ sbank,
                        const float* __restrict__ sq_b,
                        double* __restrict__ W2d,
                        double* __restrict__ sconst)
{
    int t = blockIdx.x * blockDim.x + threadIdx.x;   // 32768 threads
    int s = t & (NS - 1);
    int d = t >> 5;
    const float* wr = sq_w + (size_t)d * DIM;
    const float* br = sbank + (size_t)s * DIM;
    double acc = 0.0;
    for (int o = 0; o < DIM; ++o) acc += (double)wr[o] * (double)br[o];
    W2d[(size_t)d * NS + s] = acc * 0.03125;
    if (d == 0) {
        double c = 0.0;
        for (int o = 0; o < DIM; ++o) c += (double)sq_b[o] * (double)br[o];
        sconst[s] = c * 0.03125;
    }
}

// ---------------- helpers ----------------

__device__ __forceinline__ void fma4(float4& A, float wgt, const float4& v) {
    A.x += wgt * v.x; A.y += wgt * v.y; A.z += wgt * v.z; A.w += wgt * v.w;
}

// numpy SIMD f32 exp emulation (Cephes-derived poly, FMA Horner, rint quadrant).
__device__ __forceinline__ float np_expf(float x) {
    float m = rintf(x * 1.44269504088896341f);
    float r = fmaf(m, -0.693359375f, x);
    r = fmaf(m, 2.12194440e-4f, r);
    float y = 1.9875691500E-4f;
    y = fmaf(y, r, 1.3981999507E-3f);
    y = fmaf(y, r, 8.3334519073E-3f);
    y = fmaf(y, r, 4.1665795894E-2f);
    y = fmaf(y, r, 1.6666665459E-1f);
    y = fmaf(y, r, 5.0000001201E-1f);
    float r2 = r * r;
    y = fmaf(y, r2, r);
    y = y + 1.0f;
    return ldexpf(y, (int)m);
}

// ---------------- main fused kernel ----------------

__global__ __launch_bounds__(256, 4)
void hmb_main(const float* __restrict__ query,
              const float* __restrict__ qw,      // q_w (1024x64)
              const float* __restrict__ qb,      // q_b (64)
              const double* __restrict__ W2d,    // (1024x32) f64, pre-scaled
              const double* __restrict__ sconst, // (32) f64
              const float* __restrict__ lbank,   // (256x64)
              const float* __restrict__ dec_w,   // (64x1024)
              const float* __restrict__ dec_b,   // (1024)
              const float* __restrict__ sbank,   // (32x1024)
              float* __restrict__ out)
{
    __shared__ __align__(16) unsigned char raw[25728];
    float  (*LqF)[64]  = (float  (*)[64])(raw);            // [    0,  8192) A1->A2a
    float  (*Sc)[256]  = (float  (*)[256])(raw + 8192);    // [ 8192, 16384) quarter scores
    float  (*Wd)[256]  = (float  (*)[256])(raw);           // [    0, 16384) phase-3 overlay
    float  (*Zl)[64]   = (float  (*)[64])(raw + 16384);    // [16384, 24576)
    int    (*SWi)[4]   = (int    (*)[4])(raw + 24576);     // [24576, 25088)
    float  (*SWv)[4]   = (float  (*)[4])(raw + 25088);     // [25088, 25600)
    float  *SLT        = (float  *)(raw + 25600);          // [25600, 25728)

    const int t    = threadIdx.x;
    const int lane = t & 63;
    const int wv   = t >> 6;
    const int row0 = blockIdx.x * RPB;

    const size_t OS_SIDX = 33554432ull;
    const size_t OS_LIDX = 33685504ull;
    const size_t OS_STOP = 33947648ull;
    const size_t OS_LTOP = 34078720ull;

    // ==== phase A1 (+B1 merged): lq f32 KC=384 panels; short logits f64 alongside ====
    // q loads via a PROVABLY-UNIFORM pointer -> scalar (s_load) path
    double av0 = 0, av1 = 0, av2 = 0, av3 = 0;
    const int  sIdx = lane & 31;
    const bool hi   = lane >= 32;
    {
        const int wvu = __builtin_amdgcn_readfirstlane(wv);
        const float* qrow = query + (size_t)(row0 + 8 * wvu) * DIM;
        float lt[8] = {0, 0, 0, 0, 0, 0, 0, 0};
#pragma unroll 1
        for (int s = 0; s < 3; ++s) {
            const int dlo = s * 384;
            const int dhi = (s == 2) ? 1024 : (dlo + 384);
            float la[8] = {0, 0, 0, 0, 0, 0, 0, 0};
#pragma unroll 4
            for (int d = dlo; d < dhi; ++d) {
                float wl = qw[(size_t)d * NLAT + lane];
                float q0 = qrow[d];
                float q1 = qrow[DIM + d];
                float q2 = qrow[2 * DIM + d];
                float q3 = qrow[3 * DIM + d];
                float q4 = qrow[4 * DIM + d];
                float q5 = qrow[5 * DIM + d];
                float q6 = qrow[6 * DIM + d];
                float q7 = qrow[7 * DIM + d];
                la[0] = fmaf(q0, wl, la[0]);
                la[1] = fmaf(q1, wl, la[1]);
                la[2] = fmaf(q2, wl, la[2]);
                la[3] = fmaf(q3, wl, la[3]);
                la[4] = fmaf(q4, wl, la[4]);
                la[5] = fmaf(q5, wl, la[5]);
                la[6] = fmaf(q6, wl, la[6]);
                la[7] = fmaf(q7, wl, la[7]);
                double w2 = W2d[(size_t)d * NS + sIdx];
                av0 = fma((double)(hi ? q4 : q0), w2, av0);
                av1 = fma((double)(hi ? q5 : q1), w2, av1);
                av2 = fma((double)(hi ? q6 : q2), w2, av2);
                av3 = fma((double)(hi ? q7 : q3), w2, av3);
            }
#pragma unroll
            for (int i = 0; i < 8; ++i) lt[i] += la[i];   // panel commits ((p0+p1)+p2)
        }
        float qbl = qb[lane];
#pragma unroll
        for (int i = 0; i < 8; ++i)
            LqF[8 * wvu + i][lane] = lt[i] + qbl;
    }
    __syncthreads();   // LqF ready

    // ============ phase A2: four quarters of 8 rows ============
#pragma unroll 1
    for (int qtr = 0; qtr < 4; ++qtr) {
        // ---- A2a: scores, thread t = slot t, 8 rows (bit-exact chain per row/slot) ----
        {
            float acc[8];
#pragma unroll
            for (int rr = 0; rr < 8; ++rr) acc[rr] = 0.0f;
            const float4* lb4 = (const float4*)(lbank + (size_t)t * NLAT);
#pragma unroll 1
            for (int jq = 0; jq < 16; ++jq) {
                float4 b = lb4[jq];
#pragma unroll
                for (int rr = 0; rr < 8; ++rr) {
                    float4 q4v = *(const float4*)&LqF[8 * qtr + rr][4 * jq];
                    float a = acc[rr];
                    a = fmaf(q4v.x, b.x, a);
                    a = fmaf(q4v.y, b.y, a);
                    a = fmaf(q4v.z, b.z, a);
                    a = fmaf(q4v.w, b.w, a);
                    acc[rr] = a;
                }
            }
#pragma unroll
            for (int rr = 0; rr < 8; ++rr) Sc[rr][t] = acc[rr] * 0.125f;
        }
        __syncthreads();   // Sc ready

        // ---- A2b: 2 rows per wave ----
#pragma unroll 1
        for (int rg = 0; rg < 2; ++rg) {
            const int rh  = 2 * wv + rg;
            const int row = 8 * qtr + rh;
            const size_t grow = (size_t)(row0 + row);
            float c0 = Sc[rh][lane],       c1 = Sc[rh][lane + 64],
                  c2 = Sc[rh][lane + 128], c3 = Sc[rh][lane + 192];
            float m = fmaxf(fmaxf(c0, c1), fmaxf(c2, c3));
#pragma unroll
            for (int off = 32; off > 0; off >>= 1)
                m = fmaxf(m, __shfl_xor(m, off, 64));
            float e0 = np_expf(c0 - m), e1 = np_expf(c1 - m),
                  e2 = np_expf(c2 - m), e3 = np_expf(c3 - m);
            // denominator: exact numpy AVX512 pairwise tree via shuffles
            float A0 = e0 + __shfl_down(e0, 16, 64);
            float B0 = __shfl_down(e0, 32, 64) + __shfl_down(e0, 48, 64);
            float C0 = e1 + __shfl_down(e1, 16, 64);
            float D0 = __shfl_down(e1, 32, 64) + __shfl_down(e1, 48, 64);
            float R0 = (A0 + B0) + (C0 + D0);
            float A1_ = e2 + __shfl_down(e2, 16, 64);
            float B1_ = __shfl_down(e2, 32, 64) + __shfl_down(e2, 48, 64);
            float C1_ = e3 + __shfl_down(e3, 16, 64);
            float D1_ = __shfl_down(e3, 32, 64) + __shfl_down(e3, 48, 64);
            float R1 = (A1_ + B1_) + (C1_ + D1_);
            float t0 = R0 + __shfl_down(R0, 8, 64);
            float u0 = t0 + __shfl_down(t0, 4, 64);
            float f0 = (u0 + __shfl_down(u0, 2, 64)) + (__shfl_down(u0, 1, 64) + __shfl_down(u0, 3, 64));
            float t1 = R1 + __shfl_down(R1, 8, 64);
            float u1 = t1 + __shfl_down(t1, 4, 64);
            float f1 = (u1 + __shfl_down(u1, 2, 64)) + (__shfl_down(u1, 1, 64) + __shfl_down(u1, 3, 64));
            float sden = __shfl(f0 + f1, 0, 64);
            float v0 = e0 / sden, v1 = e1 / sden, v2 = e2 / sden, v3 = e3 / sden;
            // top-8 butterfly: strict >, lowest index on ties
            float ltv[8]; int lwi[8];
#pragma unroll
            for (int it = 0; it < 8; ++it) {
                float v = v0; int u = 0;
                if (v1 > v) { v = v1; u = 1; }
                if (v2 > v) { v = v2; u = 2; }
                if (v3 > v) { v = v3; u = 3; }
                int gi = lane + (u << 6);
#pragma unroll
                for (int off = 32; off > 0; off >>= 1) {
                    float ov = __shfl_xor(v, off, 64);
                    int og = __shfl_xor(gi, off, 64);
                    if (ov > v || (ov == v && og < gi)) { v = ov; gi = og; }
                }
                ltv[it] = v; lwi[it] = gi;
                if ((gi & 63) == lane) {
                    int wu = gi >> 6;
                    if      (wu == 0) v0 = -1.0e30f;
                    else if (wu == 1) v1 = -1.0e30f;
                    else if (wu == 2) v2 = -1.0e30f;
                    else              v3 = -1.0e30f;
                }
            }
            float zv = 0.0f;
#pragma unroll
            for (int k = 0; k < 8; ++k)
                zv += ltv[k] * lbank[(size_t)lwi[k] * NLAT + lane];
            Zl[row][lane] = zv;
            if (lane == 0) {
                SLT[row] = ltv[0]+ltv[1]+ltv[2]+ltv[3]+ltv[4]+ltv[5]+ltv[6]+ltv[7];
            } else if (lane == 1) {
                float* pi = out + OS_LIDX + grow * 8;
                float* pt = out + OS_LTOP + grow * 8;
#pragma unroll
                for (int k = 0; k < 8; ++k) { pi[k] = (float)lwi[k]; pt[k] = ltv[k]; }
            }
        }
        __syncthreads();   // Sc consumed; next quarter may overwrite
    }

    // ============ phase B2: short top-4 butterfly (av in regs, shfl broadcast) ======
    {
        double scv = sconst[sIdx];
#pragma unroll
        for (int rg = 0; rg < 8; ++rg) {
            const int r = 8 * wv + rg;
            const size_t grow = (size_t)(row0 + r);
            double avc = ((rg & 3) == 0) ? av0 : ((rg & 3) == 1) ? av1
                       : ((rg & 3) == 2) ? av2 : av3;
            int src = (lane & 31) + ((rg & 4) ? 32 : 0);
            double pv = __shfl(avc, src, 64);
            double sx0 = (lane < NS) ? (pv + scv) : -1.0e300;
            double sx = sx0;
            double swv_[4]; int swi_[4];
#pragma unroll
            for (int it = 0; it < 4; ++it) {
                double v = sx; int ix = lane;
#pragma unroll
                for (int off = 32; off > 0; off >>= 1) {
                    double ov = __shfl_xor(v, off, 64);
                    int oi = __shfl_xor(ix, off, 64);
                    if (ov > v || (ov == v && oi < ix)) { v = ov; ix = oi; }
                }
                swv_[it] = v; swi_[it] = ix;
                if (lane == ix) sx = -1.0e300;
            }
            double sm = swv_[0];
            double ssum = (lane < NS) ? (double)expf((float)(sx0 - sm)) : 0.0;
#pragma unroll
            for (int off = 32; off > 0; off >>= 1) ssum += __shfl_xor(ssum, off, 64);
            float stv[4];
#pragma unroll
            for (int it = 0; it < 4; ++it)
                stv[it] = (float)((double)expf((float)(swv_[it] - sm)) / ssum);

            if (lane == 0) {
#pragma unroll
                for (int k = 0; k < 4; ++k) { SWi[r][k] = swi_[k]; SWv[r][k] = stv[k]; }
                float* ps = out + OS_SIDX + grow * 4;
                float* pt = out + OS_STOP + grow * 4;
#pragma unroll
                for (int k = 0; k < 4; ++k) { ps[k] = (float)swi_[k]; pt[k] = stv[k]; }
            }
        }
    }

    // ============ phase 3: retrieved; dec_w staged, z via float4 LDS reads ========
    const int rgrp = t >> 6;
    const int col4 = t & 63;

#pragma unroll 1
    for (int dc = 0; dc < 4; ++dc) {
        const int cbase = dc * 256 + 4 * col4;
        float4 db = *(const float4*)(dec_b + cbase);
        float4 acc3[8];
#pragma unroll
        for (int r8 = 0; r8 < 8; ++r8) {
            const int row = rgrp * 8 + r8;
            float slt = SLT[row];
            float4 a;
            a.x = slt * db.x; a.y = slt * db.y; a.z = slt * db.z; a.w = slt * db.w;
#pragma unroll
            for (int k = 0; k < 4; ++k) {
                int   si = SWi[row][k];
                float sv = SWv[row][k];
                float4 sb = *(const float4*)(sbank + (size_t)si * DIM + cbase);
                fma4(a, sv, sb);
            }
            acc3[r8] = a;
        }
#pragma unroll 1
        for (int jh = 0; jh < 4; ++jh) {
            __syncthreads();   // prior Wd readers done before restage
#pragma unroll
            for (int i = 0; i < 4; ++i) {
                int e = t + 256 * i;           // 0..1023
                int jr = e >> 6, c4 = e & 63;
                *(float4*)&Wd[jr][4 * c4] =
                    *(const float4*)(dec_w + (size_t)(16 * jh + jr) * DIM + dc * 256 + 4 * c4);
            }
            __syncthreads();
#pragma unroll 1
            for (int j2g = 0; j2g < 4; ++j2g) {
                float4 w40 = *(const float4*)&Wd[4 * j2g + 0][4 * col4];
                float4 w41 = *(const float4*)&Wd[4 * j2g + 1][4 * col4];
                float4 w42 = *(const float4*)&Wd[4 * j2g + 2][4 * col4];
                float4 w43 = *(const float4*)&Wd[4 * j2g + 3][4 * col4];
#pragma unroll
                for (int r8 = 0; r8 < 8; ++r8) {
                    float4 zv = *(const float4*)&Zl[rgrp * 8 + r8][16 * jh + 4 * j2g];
                    fma4(acc3[r8], zv.x, w40);
                    fma4(acc3[r8], zv.y, w41);
                    fma4(acc3[r8], zv.z, w42);
                    fma4(acc3[r8], zv.w, w43);
                }
            }
        }
#pragma unroll
        for (int r8 = 0; r8 < 8; ++r8) {
            const int row = rgrp * 8 + r8;
            *(float4*)(out + (size_t)(row0 + row) * DIM + cbase) = acc3[r8];
        }
    }
}

// ---------------- launcher ----------------

extern "C" void kernel_launch(void* const* d_in, const int* in_sizes, int n_in,
                              void* d_out, int out_size, void* d_ws, size_t ws_size,
                              hipStream_t stream) {
    const float* query = (const float*)d_in[0];
    const float* sbank = (const float*)d_in[1];
    const float* lbank = (const float*)d_in[2];
    const float* dec_w = (const float*)d_in[3];
    const float* dec_b = (const float*)d_in[4];
    const float* q_w   = (const float*)d_in[5];
    const float* q_b   = (const float*)d_in[6];
    const float* sq_w  = (const float*)d_in[7];
    const float* sq_b  = (const float*)d_in[8];
    float* out = (float*)d_out;

    char* ws = (char*)d_ws;
    double* W2d    = (double*)(ws);             // [0, 262144)
    double* sconst = (double*)(ws + 262144);    // [262144, 262400)

    prep_w2 <<<dim3(128), dim3(256), 0, stream>>>(sq_w, sbank, sq_b, W2d, sconst);
    hmb_main<<<dim3(BROWS / RPB), dim3(256), 0, stream>>>(
        query, q_w, q_b, W2d, sconst, lbank, dec_w, dec_b, sbank, out);
}